// Round 1
// 188.484 us; speedup vs baseline: 1.4215x; 1.4215x over previous
//
#include <hip/hip_runtime.h>
#include <math.h>

#define GD 128  // dynamic/feature dim

// ---------------- CSR build (keyed by edge_row = aggregation destination) ----------------

__global__ __launch_bounds__(256) void csr_count(const int* __restrict__ erow, int E,
                                                 int* __restrict__ cnt) {
    int e = blockIdx.x * 256 + threadIdx.x;
    if (e < E) atomicAdd(&cnt[erow[e]], 1);  // distributed: ~10 ops/address avg
}

// block-level partial sums of cnt
__global__ __launch_bounds__(256) void scan_partial(const int* __restrict__ cnt, int N,
                                                    int* __restrict__ bsum) {
    __shared__ int s[256];
    int t = threadIdx.x;
    int i = blockIdx.x * 256 + t;
    s[t] = (i < N) ? cnt[i] : 0;
    __syncthreads();
    for (int st = 128; st > 0; st >>= 1) {
        if (t < st) s[t] += s[t + st];
        __syncthreads();
    }
    if (t == 0) bsum[blockIdx.x] = s[0];
}

// exclusive scan of nb block sums (single block, handles nb > 256 via chunks)
__global__ __launch_bounds__(256) void scan_bsum(int* __restrict__ bsum, int nb) {
    __shared__ int s[256];
    int t = threadIdx.x;
    int off = 0;
    for (int base = 0; base < nb; base += 256) {
        int v = (base + t < nb) ? bsum[base + t] : 0;
        s[t] = v;
        __syncthreads();
        for (int st = 1; st < 256; st <<= 1) {
            int u = (t >= st) ? s[t - st] : 0;
            __syncthreads();
            s[t] += u;
            __syncthreads();
        }
        if (base + t < nb) bsum[base + t] = off + s[t] - v;  // exclusive
        off += s[255];
        __syncthreads();
    }
}

// per-element exclusive scan: rowstart[i] = fillptr[i] = bsum[blk] + local exclusive
__global__ __launch_bounds__(256) void scan_final(const int* __restrict__ cnt, int N,
                                                  const int* __restrict__ bsum,
                                                  int* __restrict__ rowstart,
                                                  int* __restrict__ fillptr) {
    __shared__ int s[256];
    int t = threadIdx.x;
    int i = blockIdx.x * 256 + t;
    int v = (i < N) ? cnt[i] : 0;
    s[t] = v;
    __syncthreads();
    for (int st = 1; st < 256; st <<= 1) {
        int u = (t >= st) ? s[t - st] : 0;
        __syncthreads();
        s[t] += u;
        __syncthreads();
    }
    if (i < N) {
        int excl = bsum[blockIdx.x] + s[t] - v;
        rowstart[i] = excl;
        fillptr[i] = excl;
    }
}

__global__ __launch_bounds__(256) void csr_fill(const int* __restrict__ erow,
                                                const int* __restrict__ ecol,
                                                const float* __restrict__ ev, int E,
                                                int* __restrict__ fillptr,
                                                int* __restrict__ ccol,
                                                float* __restrict__ cval) {
    int e = blockIdx.x * 256 + threadIdx.x;
    if (e >= E) return;
    int p = atomicAdd(&fillptr[erow[e]], 1);  // distributed
    ccol[p] = ecol[e];
    cval[p] = ev[e];
}

// ---------------- frontier expansion & compaction ----------------

// for each b: mark all CSR-cols of row codeid[b]
__global__ __launch_bounds__(64) void expand_codeid(const int* __restrict__ codeid,
                                                    const int* __restrict__ rowstart,
                                                    const int* __restrict__ cnt,
                                                    const int* __restrict__ ccol,
                                                    int* __restrict__ mark) {
    int r = codeid[blockIdx.x];
    int s = rowstart[r], c = cnt[r];
    for (int k = threadIdx.x; k < c; k += 64) mark[ccol[s + k]] = 1;
}

// for each row in rows[0..*cntp): mark all its CSR-cols
__global__ __launch_bounds__(64) void expand_rows(const int* __restrict__ rows,
                                                  const int* __restrict__ cntp,
                                                  const int* __restrict__ rowstart,
                                                  const int* __restrict__ cnt,
                                                  const int* __restrict__ ccol,
                                                  int* __restrict__ mark) {
    int n = *cntp;
    for (int i = blockIdx.x; i < n; i += gridDim.x) {
        int r = rows[i];
        int s = rowstart[r], c = cnt[r];
        for (int k = threadIdx.x; k < c; k += 64) mark[ccol[s + k]] = 1;
    }
}

// compact marked indices; one leader atomic per block (235 blocks total)
__global__ __launch_bounds__(256) void compact_marked(const int* __restrict__ mark, int N,
                                                      int* __restrict__ rows,
                                                      int* __restrict__ cntp) {
    __shared__ int woff[4];
    __shared__ int base;
    int t = threadIdx.x;
    int i = blockIdx.x * 256 + t;
    int m = (i < N) ? mark[i] : 0;
    unsigned long long ball = __ballot(m != 0);
    int wid = t >> 6, lane = t & 63;
    if (lane == 0) woff[wid] = __popcll(ball);
    __syncthreads();
    if (t == 0) {
        int c0 = woff[0], c1 = woff[1], c2 = woff[2], c3 = woff[3];
        int tot = c0 + c1 + c2 + c3;
        base = tot ? atomicAdd(cntp, tot) : 0;
        woff[0] = 0; woff[1] = c0; woff[2] = c0 + c1; woff[3] = c0 + c1 + c2;
    }
    __syncthreads();
    if (m) rows[base + woff[wid] + __popcll(ball & ((1ULL << lane) - 1ULL))] = i;
}

// ---------------- compute kernels ----------------

// Y[rows[i]] = X[rows[i]] @ W for i < *cntp. 8 rows/block-iteration, 32 thr/row.
__global__ __launch_bounds__(256) void gemm_rows(const float* __restrict__ X,
                                                 const float* __restrict__ W,
                                                 float* __restrict__ Y,
                                                 const int* __restrict__ rows,
                                                 const int* __restrict__ cntp) {
    __shared__ float xs[8 * GD];
    __shared__ int rid[8];
    int t = threadIdx.x;
    int cnt = *cntp;
    int ngroups = (cnt + 7) >> 3;
    for (int g = blockIdx.x; g < ngroups; g += gridDim.x) {
        if (t < 8) {
            int gi = g * 8 + t;
            rid[t] = (gi < cnt) ? rows[gi] : -1;
        }
        __syncthreads();
        int r = rid[t >> 5];
        if (r >= 0) ((float4*)xs)[t] = ((const float4*)(X + (size_t)r * GD))[t & 31];
        __syncthreads();
        int c4 = (t & 31) * 4;
        const float* xrow = xs + (t >> 5) * GD;
        float a0 = 0.f, a1 = 0.f, a2 = 0.f, a3 = 0.f;
#pragma unroll 8
        for (int k = 0; k < GD; ++k) {
            float xv = xrow[k];
            float4 w = *(const float4*)(W + k * GD + c4);
            a0 += xv * w.x; a1 += xv * w.y; a2 += xv * w.z; a3 += xv * w.w;
        }
        if (r >= 0) *(float4*)(Y + (size_t)r * GD + c4) = make_float4(a0, a1, a2, a3);
    }
}

// gather-based aggregation + alpha-blend + relu (replaces zero+scatter+blend, no atomics):
// out[r] = relu(0.1 * sum_{e in CSR[r]} S[ccol[e]] * cval[e] + 0.9 * init[r]) for r in rows
__global__ __launch_bounds__(128) void agg_blend(const float* __restrict__ S,
                                                 const float* __restrict__ init,
                                                 const int* __restrict__ rowstart,
                                                 const int* __restrict__ cnt,
                                                 const int* __restrict__ ccol,
                                                 const float* __restrict__ cval,
                                                 const int* __restrict__ rows,
                                                 const int* __restrict__ cntp,
                                                 float* __restrict__ out) {
    int t = threadIdx.x;
    int n = *cntp;
    for (int i = blockIdx.x; i < n; i += gridDim.x) {
        int r = rows[i];
        int s = rowstart[r], c = cnt[r];
        float acc = 0.f;
        for (int k = 0; k < c; ++k) {
            int col = ccol[s + k];          // uniform across block -> broadcast
            float v = cval[s + k];
            acc += S[(size_t)col * GD + t] * v;  // coalesced 512B row read
        }
        out[(size_t)r * GD + t] = fmaxf(0.1f * acc + 0.9f * init[(size_t)r * GD + t], 0.0f);
    }
}

// layer-2 aggregation fused into RNNCell + L2 normalize. One block (128 thr) per b.
__global__ __launch_bounds__(128) void final_rnn(const float* __restrict__ S2,
                                                 const float* __restrict__ init,
                                                 const float* __restrict__ patient,
                                                 const float* __restrict__ timediffs,
                                                 const float* __restrict__ features,
                                                 const float* __restrict__ W_ih,
                                                 const float* __restrict__ b_ih,
                                                 const float* __restrict__ W_hh,
                                                 const float* __restrict__ b_hh,
                                                 const int* __restrict__ codeid,
                                                 const int* __restrict__ patientid,
                                                 const int* __restrict__ rowstart,
                                                 const int* __restrict__ cnt,
                                                 const int* __restrict__ ccol,
                                                 const float* __restrict__ cval,
                                                 float* __restrict__ out) {
    __shared__ float in1[257];
    __shared__ float ce[GD];
    __shared__ float red[GD];
    int b = blockIdx.x;
    int j = threadIdx.x;
    int cid = codeid[b];
    int pid = patientid[0];

    // agg2[cid][j] = sum over CSR[cid] of S2[col] * val   (gather, no atomics)
    int s = rowstart[cid], c = cnt[cid];
    float agg = 0.f;
    for (int k = 0; k < c; ++k)
        agg += cval[s + k] * S2[(size_t)ccol[s + k] * GD + j];

    ce[j] = fmaxf(0.1f * agg + 0.9f * init[(size_t)cid * GD + j], 0.0f);
    in1[j] = patient[(size_t)pid * GD + j];
    in1[GD + 1 + j] = features[(size_t)b * GD + j];
    if (j == 0) in1[GD] = timediffs[b];
    __syncthreads();

    float acc = b_ih[j] + b_hh[j];
    const float* wih = W_ih + (size_t)j * 257;
#pragma unroll 8
    for (int k = 0; k < 257; ++k) acc += in1[k] * wih[k];
    const float* whh = W_hh + (size_t)j * GD;
#pragma unroll 8
    for (int k = 0; k < GD; ++k) acc += ce[k] * whh[k];
    float h = tanhf(acc);

    red[j] = h * h;
    __syncthreads();
    for (int st = 64; st > 0; st >>= 1) {
        if (j < st) red[j] += red[j + st];
        __syncthreads();
    }
    float nrm = fmaxf(sqrtf(red[0]), 1e-12f);
    out[(size_t)b * GD + j] = h / nrm;
}

extern "C" void kernel_launch(void* const* d_in, const int* in_sizes, int n_in,
                              void* d_out, int out_size, void* d_ws, size_t ws_size,
                              hipStream_t stream) {
    const float* code_dynamic = (const float*)d_in[0];
    const float* init_cd      = (const float*)d_in[1];
    const float* patient      = (const float*)d_in[2];
    const float* timediffs    = (const float*)d_in[3];
    const float* features     = (const float*)d_in[4];
    const float* edge_val     = (const float*)d_in[5];
    const float* W1           = (const float*)d_in[6];
    const float* W2           = (const float*)d_in[7];
    const float* W_ih         = (const float*)d_in[8];
    const float* b_ih         = (const float*)d_in[9];
    const float* W_hh         = (const float*)d_in[10];
    const float* b_hh         = (const float*)d_in[11];
    const int* edge_row       = (const int*)d_in[12];
    const int* edge_col       = (const int*)d_in[13];
    const int* codeid         = (const int*)d_in[14];
    const int* patientid      = (const int*)d_in[15];

    int N = in_sizes[0] / GD;   // 60000
    int E = in_sizes[5];        // 600000
    int B = in_sizes[14];       // 256
    size_t nd = (size_t)N * GD;

    // workspace layout
    float* bufA    = (float*)d_ws;           // support1 then support2 (N*128 f32)
    float* bufB    = bufA + nd;              // x1 (N*128 f32)
    int*   ccol    = (int*)(bufB + nd);      // E   CSR cols
    float* cval    = (float*)(ccol + E);     // E   CSR vals
    int*   cntarr  = (int*)(cval + E);       // N   -- zeroed region starts here
    int*   mark1   = cntarr + N;             // N
    int*   mark0   = mark1 + N;              // N
    int*   cnts    = mark0 + N;              // 8 ints: [cntR1, cntR0] -- end of zeroed region
    int*   rowstart= cnts + 8;               // N
    int*   fillptr = rowstart + N;           // N
    int*   rows1   = fillptr + N;            // N
    int*   rows0   = rows1 + N;              // N
    int*   bsum    = rows0 + N;              // ceil(N/256)

    hipMemsetAsync(cntarr, 0, ((size_t)3 * N + 8) * sizeof(int), stream);

    int eb  = (E + 255) / 256;
    int nbs = (N + 255) / 256;

    // CSR build: histogram -> exclusive scan -> fill
    csr_count <<<eb, 256, 0, stream>>>(edge_row, E, cntarr);
    scan_partial<<<nbs, 256, 0, stream>>>(cntarr, N, bsum);
    scan_bsum <<<1, 256, 0, stream>>>(bsum, nbs);
    scan_final<<<nbs, 256, 0, stream>>>(cntarr, N, bsum, rowstart, fillptr);
    csr_fill  <<<eb, 256, 0, stream>>>(edge_row, edge_col, edge_val, E, fillptr, ccol, cval);

    // dependency cone: codeid rows -> rows1 (their CSR cols) -> rows0 (rows1's CSR cols)
    expand_codeid<<<B, 64, 0, stream>>>(codeid, rowstart, cntarr, ccol, mark1);
    compact_marked<<<nbs, 256, 0, stream>>>(mark1, N, rows1, &cnts[0]);
    expand_rows<<<2048, 64, 0, stream>>>(rows1, &cnts[0], rowstart, cntarr, ccol, mark0);
    compact_marked<<<nbs, 256, 0, stream>>>(mark0, N, rows0, &cnts[1]);

    // layer 1: support1 on rows0, gather-agg + blend + relu on rows1
    gemm_rows<<<1024, 256, 0, stream>>>(code_dynamic, W1, bufA, rows0, &cnts[1]);
    agg_blend<<<2048, 128, 0, stream>>>(bufA, init_cd, rowstart, cntarr, ccol, cval,
                                        rows1, &cnts[0], bufB);

    // layer 2: support2 on rows1 (aggregation for codeid rows is fused into final_rnn)
    gemm_rows<<<1024, 256, 0, stream>>>(bufB, W2, bufA, rows1, &cnts[0]);

    // RNNCell + L2 normalize (with fused layer-2 gather-aggregation)
    final_rnn<<<B, 128, 0, stream>>>(bufA, init_cd, patient, timediffs, features,
                                     W_ih, b_ih, W_hh, b_hh, codeid, patientid,
                                     rowstart, cntarr, ccol, cval,
                                     (float*)d_out);
}

// Round 2
// 132.050 us; speedup vs baseline: 2.0290x; 1.4274x over previous
//
#include <hip/hip_runtime.h>
#include <math.h>

#define GD 128  // dynamic/feature dim

// ---------------- frontier marking (no atomics) ----------------

__global__ __launch_bounds__(256) void mark_codeids(const int* __restrict__ codeid, int B,
                                                    int* __restrict__ mark2,
                                                    int* __restrict__ markU) {
    int i = blockIdx.x * 256 + threadIdx.x;
    if (i < B) {
        int c = codeid[i];
        mark2[c] = 1;
        markU[c] = 1;
    }
}

// markOut[ecol[e]] = 1 for edges whose source row is marked. Plain stores, benign races.
__global__ __launch_bounds__(256) void mark_next(const int* __restrict__ erow,
                                                 const int* __restrict__ ecol, int E,
                                                 const int* __restrict__ markIn,
                                                 int* __restrict__ markOut) {
    int e = blockIdx.x * 256 + threadIdx.x;
    if (e < E && markIn[erow[e]]) markOut[ecol[e]] = 1;
}

// Combined: expand markU -> mark0 AND histogram restricted CSR row counts.
// Atomics are distributed over ~2.7K counters (~10 adds each).
__global__ __launch_bounds__(256) void expand_and_count(const int* __restrict__ erow,
                                                        const int* __restrict__ ecol, int E,
                                                        const int* __restrict__ markU,
                                                        int* __restrict__ mark0,
                                                        int* __restrict__ cnt) {
    int e = blockIdx.x * 256 + threadIdx.x;
    if (e >= E) return;
    int r = erow[e];
    if (markU[r]) {
        mark0[ecol[e]] = 1;
        atomicAdd(&cnt[r], 1);
    }
}

// ---------------- exclusive scan over N (restricted counts; mostly zeros) ----------------

__global__ __launch_bounds__(256) void scan_partial(const int* __restrict__ cnt, int N,
                                                    int* __restrict__ bsum) {
    __shared__ int s[256];
    int t = threadIdx.x;
    int i = blockIdx.x * 256 + t;
    s[t] = (i < N) ? cnt[i] : 0;
    __syncthreads();
    for (int st = 128; st > 0; st >>= 1) {
        if (t < st) s[t] += s[t + st];
        __syncthreads();
    }
    if (t == 0) bsum[blockIdx.x] = s[0];
}

__global__ __launch_bounds__(256) void scan_bsum(int* __restrict__ bsum, int nb) {
    __shared__ int s[256];
    int t = threadIdx.x;
    int off = 0;
    for (int base = 0; base < nb; base += 256) {
        int v = (base + t < nb) ? bsum[base + t] : 0;
        s[t] = v;
        __syncthreads();
        for (int st = 1; st < 256; st <<= 1) {
            int u = (t >= st) ? s[t - st] : 0;
            __syncthreads();
            s[t] += u;
            __syncthreads();
        }
        if (base + t < nb) bsum[base + t] = off + s[t] - v;  // exclusive
        off += s[255];
        __syncthreads();
    }
}

__global__ __launch_bounds__(256) void scan_final(const int* __restrict__ cnt, int N,
                                                  const int* __restrict__ bsum,
                                                  int* __restrict__ rowstart,
                                                  int* __restrict__ fillptr) {
    __shared__ int s[256];
    int t = threadIdx.x;
    int i = blockIdx.x * 256 + t;
    int v = (i < N) ? cnt[i] : 0;
    s[t] = v;
    __syncthreads();
    for (int st = 1; st < 256; st <<= 1) {
        int u = (t >= st) ? s[t - st] : 0;
        __syncthreads();
        s[t] += u;
        __syncthreads();
    }
    if (i < N) {
        int excl = bsum[blockIdx.x] + s[t] - v;
        rowstart[i] = excl;
        fillptr[i] = excl;
    }
}

// restricted CSR fill: only edges with marked source row (~27K of 600K)
__global__ __launch_bounds__(256) void csr_fill(const int* __restrict__ erow,
                                                const int* __restrict__ ecol,
                                                const float* __restrict__ ev, int E,
                                                const int* __restrict__ markU,
                                                int* __restrict__ fillptr,
                                                int* __restrict__ ccol,
                                                float* __restrict__ cval) {
    int e = blockIdx.x * 256 + threadIdx.x;
    if (e >= E) return;
    int r = erow[e];
    if (!markU[r]) return;
    int p = atomicAdd(&fillptr[r], 1);  // distributed (~10 per address)
    ccol[p] = ecol[e];
    cval[p] = ev[e];
}

// compact two mark arrays in one pass; one leader atomic per block per list
__global__ __launch_bounds__(256) void compact2(const int* __restrict__ markA,
                                                const int* __restrict__ markB, int N,
                                                int* __restrict__ rowsA, int* __restrict__ cntA,
                                                int* __restrict__ rowsB, int* __restrict__ cntB) {
    __shared__ int woff[4];
    __shared__ int base;
    int t = threadIdx.x;
    int i = blockIdx.x * 256 + t;
    int wid = t >> 6, lane = t & 63;

    // list A
    int m = (i < N) ? markA[i] : 0;
    unsigned long long ball = __ballot(m != 0);
    if (lane == 0) woff[wid] = __popcll(ball);
    __syncthreads();
    if (t == 0) {
        int c0 = woff[0], c1 = woff[1], c2 = woff[2], c3 = woff[3];
        int tot = c0 + c1 + c2 + c3;
        base = tot ? atomicAdd(cntA, tot) : 0;
        woff[0] = 0; woff[1] = c0; woff[2] = c0 + c1; woff[3] = c0 + c1 + c2;
    }
    __syncthreads();
    if (m) rowsA[base + woff[wid] + __popcll(ball & ((1ULL << lane) - 1ULL))] = i;
    __syncthreads();

    // list B
    m = (i < N) ? markB[i] : 0;
    ball = __ballot(m != 0);
    if (lane == 0) woff[wid] = __popcll(ball);
    __syncthreads();
    if (t == 0) {
        int c0 = woff[0], c1 = woff[1], c2 = woff[2], c3 = woff[3];
        int tot = c0 + c1 + c2 + c3;
        base = tot ? atomicAdd(cntB, tot) : 0;
        woff[0] = 0; woff[1] = c0; woff[2] = c0 + c1; woff[3] = c0 + c1 + c2;
    }
    __syncthreads();
    if (m) rowsB[base + woff[wid] + __popcll(ball & ((1ULL << lane) - 1ULL))] = i;
}

// ---------------- compute kernels ----------------

// Y[rows[i]] = X[rows[i]] @ W. 32 rows/block-iteration; each thread: 4 rows x 4 cols
// -> 16 independent FMA chains, W float4 shared by 32 rows (4x less redundant than v1).
__global__ __launch_bounds__(256) void gemm_rows(const float* __restrict__ X,
                                                 const float* __restrict__ W,
                                                 float* __restrict__ Y,
                                                 const int* __restrict__ rows,
                                                 const int* __restrict__ cntp) {
    __shared__ float xs[32 * GD];  // 16 KB
    __shared__ int rid[32];
    int t = threadIdx.x;
    int cnt = *cntp;
    int ngroups = (cnt + 31) >> 5;
    for (int g = blockIdx.x; g < ngroups; g += gridDim.x) {
        __syncthreads();  // protect xs/rid reuse across grid-stride iterations
        if (t < 32) {
            int gi = g * 32 + t;
            rid[t] = (gi < cnt) ? rows[gi] : -1;
        }
        __syncthreads();
        // stage 32 rows (row-major), coalesced: 32 consecutive lanes read one row
        for (int u = t; u < 32 * 32; u += 256) {
            int r = rid[u >> 5];
            if (r >= 0) ((float4*)xs)[u] = ((const float4*)(X + (size_t)r * GD))[u & 31];
        }
        __syncthreads();

        int c4 = (t & 31) * 4;
        int rg = (t >> 5) * 4;  // rows rg..rg+3
        float4 a0 = {0, 0, 0, 0}, a1 = {0, 0, 0, 0}, a2 = {0, 0, 0, 0}, a3 = {0, 0, 0, 0};
        const float* x0 = xs + (size_t)(rg + 0) * GD;
        const float* x1 = xs + (size_t)(rg + 1) * GD;
        const float* x2 = xs + (size_t)(rg + 2) * GD;
        const float* x3 = xs + (size_t)(rg + 3) * GD;
#pragma unroll 4
        for (int k = 0; k < GD; k += 4) {
            float4 xv0 = *(const float4*)(x0 + k);
            float4 xv1 = *(const float4*)(x1 + k);
            float4 xv2 = *(const float4*)(x2 + k);
            float4 xv3 = *(const float4*)(x3 + k);
            float4 w0 = *(const float4*)(W + (size_t)(k + 0) * GD + c4);
            float4 w1 = *(const float4*)(W + (size_t)(k + 1) * GD + c4);
            float4 w2 = *(const float4*)(W + (size_t)(k + 2) * GD + c4);
            float4 w3 = *(const float4*)(W + (size_t)(k + 3) * GD + c4);
            a0.x += xv0.x * w0.x + xv0.y * w1.x + xv0.z * w2.x + xv0.w * w3.x;
            a0.y += xv0.x * w0.y + xv0.y * w1.y + xv0.z * w2.y + xv0.w * w3.y;
            a0.z += xv0.x * w0.z + xv0.y * w1.z + xv0.z * w2.z + xv0.w * w3.z;
            a0.w += xv0.x * w0.w + xv0.y * w1.w + xv0.z * w2.w + xv0.w * w3.w;
            a1.x += xv1.x * w0.x + xv1.y * w1.x + xv1.z * w2.x + xv1.w * w3.x;
            a1.y += xv1.x * w0.y + xv1.y * w1.y + xv1.z * w2.y + xv1.w * w3.y;
            a1.z += xv1.x * w0.z + xv1.y * w1.z + xv1.z * w2.z + xv1.w * w3.z;
            a1.w += xv1.x * w0.w + xv1.y * w1.w + xv1.z * w2.w + xv1.w * w3.w;
            a2.x += xv2.x * w0.x + xv2.y * w1.x + xv2.z * w2.x + xv2.w * w3.x;
            a2.y += xv2.x * w0.y + xv2.y * w1.y + xv2.z * w2.y + xv2.w * w3.y;
            a2.z += xv2.x * w0.z + xv2.y * w1.z + xv2.z * w2.z + xv2.w * w3.z;
            a2.w += xv2.x * w0.w + xv2.y * w1.w + xv2.z * w2.w + xv2.w * w3.w;
            a3.x += xv3.x * w0.x + xv3.y * w1.x + xv3.z * w2.x + xv3.w * w3.x;
            a3.y += xv3.x * w0.y + xv3.y * w1.y + xv3.z * w2.y + xv3.w * w3.y;
            a3.z += xv3.x * w0.z + xv3.y * w1.z + xv3.z * w2.z + xv3.w * w3.z;
            a3.w += xv3.x * w0.w + xv3.y * w1.w + xv3.z * w2.w + xv3.w * w3.w;
        }
        int r;
        r = rid[rg + 0]; if (r >= 0) *(float4*)(Y + (size_t)r * GD + c4) = a0;
        r = rid[rg + 1]; if (r >= 0) *(float4*)(Y + (size_t)r * GD + c4) = a1;
        r = rid[rg + 2]; if (r >= 0) *(float4*)(Y + (size_t)r * GD + c4) = a2;
        r = rid[rg + 3]; if (r >= 0) *(float4*)(Y + (size_t)r * GD + c4) = a3;
    }
}

// gather aggregation + alpha-blend + relu over listed rows (no atomics)
__global__ __launch_bounds__(128) void agg_blend(const float* __restrict__ S,
                                                 const float* __restrict__ init,
                                                 const int* __restrict__ rowstart,
                                                 const int* __restrict__ cnt,
                                                 const int* __restrict__ ccol,
                                                 const float* __restrict__ cval,
                                                 const int* __restrict__ rows,
                                                 const int* __restrict__ cntp,
                                                 float* __restrict__ out) {
    int t = threadIdx.x;
    int n = *cntp;
    for (int i = blockIdx.x; i < n; i += gridDim.x) {
        int r = rows[i];
        int s = rowstart[r], c = cnt[r];
        float acc = 0.f;
        for (int k = 0; k < c; ++k) {
            int col = ccol[s + k];               // uniform -> broadcast
            float v = cval[s + k];
            acc += S[(size_t)col * GD + t] * v;  // coalesced 512B row read
        }
        out[(size_t)r * GD + t] = fmaxf(0.1f * acc + 0.9f * init[(size_t)r * GD + t], 0.0f);
    }
}

// layer-2 aggregation fused into RNNCell + L2 normalize. One block (128 thr) per b.
__global__ __launch_bounds__(128) void final_rnn(const float* __restrict__ S2,
                                                 const float* __restrict__ init,
                                                 const float* __restrict__ patient,
                                                 const float* __restrict__ timediffs,
                                                 const float* __restrict__ features,
                                                 const float* __restrict__ W_ih,
                                                 const float* __restrict__ b_ih,
                                                 const float* __restrict__ W_hh,
                                                 const float* __restrict__ b_hh,
                                                 const int* __restrict__ codeid,
                                                 const int* __restrict__ patientid,
                                                 const int* __restrict__ rowstart,
                                                 const int* __restrict__ cnt,
                                                 const int* __restrict__ ccol,
                                                 const float* __restrict__ cval,
                                                 float* __restrict__ out) {
    __shared__ float in1[257];
    __shared__ float ce[GD];
    __shared__ float red[GD];
    int b = blockIdx.x;
    int j = threadIdx.x;
    int cid = codeid[b];
    int pid = patientid[0];

    int s = rowstart[cid], c = cnt[cid];
    float agg = 0.f;
    for (int k = 0; k < c; ++k)
        agg += cval[s + k] * S2[(size_t)ccol[s + k] * GD + j];

    ce[j] = fmaxf(0.1f * agg + 0.9f * init[(size_t)cid * GD + j], 0.0f);
    in1[j] = patient[(size_t)pid * GD + j];
    in1[GD + 1 + j] = features[(size_t)b * GD + j];
    if (j == 0) in1[GD] = timediffs[b];
    __syncthreads();

    float acc = b_ih[j] + b_hh[j];
    const float* wih = W_ih + (size_t)j * 257;
#pragma unroll 8
    for (int k = 0; k < 257; ++k) acc += in1[k] * wih[k];
    const float* whh = W_hh + (size_t)j * GD;
#pragma unroll 8
    for (int k = 0; k < GD; ++k) acc += ce[k] * whh[k];
    float h = tanhf(acc);

    red[j] = h * h;
    __syncthreads();
    for (int st = 64; st > 0; st >>= 1) {
        if (j < st) red[j] += red[j + st];
        __syncthreads();
    }
    float nrm = fmaxf(sqrtf(red[0]), 1e-12f);
    out[(size_t)b * GD + j] = h / nrm;
}

extern "C" void kernel_launch(void* const* d_in, const int* in_sizes, int n_in,
                              void* d_out, int out_size, void* d_ws, size_t ws_size,
                              hipStream_t stream) {
    const float* code_dynamic = (const float*)d_in[0];
    const float* init_cd      = (const float*)d_in[1];
    const float* patient      = (const float*)d_in[2];
    const float* timediffs    = (const float*)d_in[3];
    const float* features     = (const float*)d_in[4];
    const float* edge_val     = (const float*)d_in[5];
    const float* W1           = (const float*)d_in[6];
    const float* W2           = (const float*)d_in[7];
    const float* W_ih         = (const float*)d_in[8];
    const float* b_ih         = (const float*)d_in[9];
    const float* W_hh         = (const float*)d_in[10];
    const float* b_hh         = (const float*)d_in[11];
    const int* edge_row       = (const int*)d_in[12];
    const int* edge_col       = (const int*)d_in[13];
    const int* codeid         = (const int*)d_in[14];
    const int* patientid      = (const int*)d_in[15];

    int N = in_sizes[0] / GD;   // 60000
    int E = in_sizes[5];        // 600000
    int B = in_sizes[14];       // 256
    size_t nd = (size_t)N * GD;

    // workspace layout
    float* bufA    = (float*)d_ws;           // support1 / support2 (N*128 f32)
    float* bufB    = bufA + nd;              // x1 (N*128 f32)
    int*   ccol    = (int*)(bufB + nd);      // E  restricted CSR cols (compacted)
    float* cval    = (float*)(ccol + E);     // E  restricted CSR vals
    int*   cntarr  = (int*)(cval + E);       // N  -- zeroed region start
    int*   mark2   = cntarr + N;             // N  codeid rows
    int*   markU   = mark2 + N;              // N  rows1 u codeid (need CSR + x1)
    int*   mark0   = markU + N;              // N  rows needing layer-1 gemm
    int*   cnts    = mark0 + N;              // 8 ints: [cntU, cnt0] -- zeroed region end
    int*   rowstart= cnts + 8;               // N
    int*   fillptr = rowstart + N;           // N
    int*   rowsU   = fillptr + N;            // N
    int*   rows0   = rowsU + N;              // N
    int*   bsum    = rows0 + N;              // ceil(N/256)

    hipMemsetAsync(cntarr, 0, ((size_t)4 * N + 8) * sizeof(int), stream);

    int eb  = (E + 255) / 256;
    int nbs = (N + 255) / 256;

    // dependency cone via mark propagation (no contended atomics, no full CSR)
    mark_codeids<<<(B + 255) / 256, 256, 0, stream>>>(codeid, B, mark2, markU);
    mark_next<<<eb, 256, 0, stream>>>(edge_row, edge_col, E, mark2, markU);
    expand_and_count<<<eb, 256, 0, stream>>>(edge_row, edge_col, E, markU, mark0, cntarr);

    // restricted CSR: exclusive scan of counts, then fill (~27K edges)
    scan_partial<<<nbs, 256, 0, stream>>>(cntarr, N, bsum);
    scan_bsum<<<1, 256, 0, stream>>>(bsum, nbs);
    scan_final<<<nbs, 256, 0, stream>>>(cntarr, N, bsum, rowstart, fillptr);
    csr_fill<<<eb, 256, 0, stream>>>(edge_row, edge_col, edge_val, E, markU, fillptr, ccol, cval);

    compact2<<<nbs, 256, 0, stream>>>(markU, mark0, N, rowsU, &cnts[0], rows0, &cnts[1]);

    // layer 1: support1 on rows0 (~27K rows), gather-agg + blend + relu on rowsU (~2.7K)
    gemm_rows<<<1024, 256, 0, stream>>>(code_dynamic, W1, bufA, rows0, &cnts[1]);
    agg_blend<<<2048, 128, 0, stream>>>(bufA, init_cd, rowstart, cntarr, ccol, cval,
                                        rowsU, &cnts[0], bufB);

    // layer 2: support2 on rowsU (codeid-row aggregation fused into final_rnn)
    gemm_rows<<<1024, 256, 0, stream>>>(bufB, W2, bufA, rowsU, &cnts[0]);

    // RNNCell + L2 normalize (fused layer-2 gather-aggregation)
    final_rnn<<<B, 128, 0, stream>>>(bufA, init_cd, patient, timediffs, features,
                                     W_ih, b_ih, W_hh, b_hh, codeid, patientid,
                                     rowstart, cntarr, ccol, cval,
                                     (float*)d_out);
}

// Round 3
// 128.611 us; speedup vs baseline: 2.0832x; 1.0267x over previous
//
#include <hip/hip_runtime.h>
#include <math.h>

#define GD 128  // dynamic/feature dim

// ---------------- workspace zeroing (replaces pathologically slow runtime fill) ----------------

__global__ __launch_bounds__(256) void zero_ints(int4* __restrict__ p, int n4) {
    int i = blockIdx.x * 256 + threadIdx.x;
    if (i < n4) p[i] = make_int4(0, 0, 0, 0);
}

// ---------------- frontier marking (no atomics) ----------------

__global__ __launch_bounds__(256) void mark_codeids(const int* __restrict__ codeid, int B,
                                                    int* __restrict__ mark2,
                                                    int* __restrict__ markU) {
    int i = blockIdx.x * 256 + threadIdx.x;
    if (i < B) {
        int c = codeid[i];
        mark2[c] = 1;
        markU[c] = 1;
    }
}

// markOut[ecol[e]] = 1 for edges whose source row is marked. Plain stores, benign races.
__global__ __launch_bounds__(256) void mark_next(const int* __restrict__ erow,
                                                 const int* __restrict__ ecol, int E,
                                                 const int* __restrict__ markIn,
                                                 int* __restrict__ markOut) {
    int e = blockIdx.x * 256 + threadIdx.x;
    if (e < E && markIn[erow[e]]) markOut[ecol[e]] = 1;
}

// Combined: expand markU -> mark0 AND histogram restricted CSR row counts.
// Atomics are distributed over ~2.8K counters (~10 adds each).
__global__ __launch_bounds__(256) void expand_and_count(const int* __restrict__ erow,
                                                        const int* __restrict__ ecol, int E,
                                                        const int* __restrict__ markU,
                                                        int* __restrict__ mark0,
                                                        int* __restrict__ cnt) {
    int e = blockIdx.x * 256 + threadIdx.x;
    if (e >= E) return;
    int r = erow[e];
    if (markU[r]) {
        mark0[ecol[e]] = 1;
        atomicAdd(&cnt[r], 1);
    }
}

// ---------------- fused CSR-offset allocation + dual compaction (one N-pass) ----------------
// CSR segment placement is arbitrary (fill order is atomic-nondeterministic anyway), so
// inter-block offsets come from one leader atomicAdd per block instead of a 3-kernel scan.
__global__ __launch_bounds__(256) void scan_compact(const int* __restrict__ cnt,
                                                    const int* __restrict__ markU,
                                                    const int* __restrict__ mark0, int N,
                                                    int* __restrict__ rowstart,
                                                    int* __restrict__ fillptr,
                                                    int* __restrict__ gAlloc,
                                                    int* __restrict__ rowsU, int* __restrict__ cntU,
                                                    int* __restrict__ rows0, int* __restrict__ cnt0) {
    __shared__ int s[256];
    __shared__ int sbase;
    __shared__ int woff[4];
    __shared__ int cbase;
    int t = threadIdx.x;
    int i = blockIdx.x * 256 + t;
    int wid = t >> 6, lane = t & 63;

    // --- CSR offsets: block-local exclusive scan + one allocator atomic ---
    int v = (i < N) ? cnt[i] : 0;
    s[t] = v;
    __syncthreads();
    for (int st = 1; st < 256; st <<= 1) {
        int u = (t >= st) ? s[t - st] : 0;
        __syncthreads();
        s[t] += u;
        __syncthreads();
    }
    if (t == 255) sbase = s[255] ? atomicAdd(gAlloc, s[255]) : 0;
    __syncthreads();
    if (i < N && v > 0) {
        int rs = sbase + s[t] - v;
        rowstart[i] = rs;
        fillptr[i] = rs;
    }

    // --- compact markU -> rowsU ---
    int m = (i < N) ? markU[i] : 0;
    unsigned long long ball = __ballot(m != 0);
    if (lane == 0) woff[wid] = __popcll(ball);
    __syncthreads();
    if (t == 0) {
        int c0 = woff[0], c1 = woff[1], c2 = woff[2], c3 = woff[3];
        int tot = c0 + c1 + c2 + c3;
        cbase = tot ? atomicAdd(cntU, tot) : 0;
        woff[0] = 0; woff[1] = c0; woff[2] = c0 + c1; woff[3] = c0 + c1 + c2;
    }
    __syncthreads();
    if (m) rowsU[cbase + woff[wid] + __popcll(ball & ((1ULL << lane) - 1ULL))] = i;
    __syncthreads();

    // --- compact mark0 -> rows0 ---
    m = (i < N) ? mark0[i] : 0;
    ball = __ballot(m != 0);
    if (lane == 0) woff[wid] = __popcll(ball);
    __syncthreads();
    if (t == 0) {
        int c0 = woff[0], c1 = woff[1], c2 = woff[2], c3 = woff[3];
        int tot = c0 + c1 + c2 + c3;
        cbase = tot ? atomicAdd(cnt0, tot) : 0;
        woff[0] = 0; woff[1] = c0; woff[2] = c0 + c1; woff[3] = c0 + c1 + c2;
    }
    __syncthreads();
    if (m) rows0[cbase + woff[wid] + __popcll(ball & ((1ULL << lane) - 1ULL))] = i;
}

// restricted CSR fill: only edges with marked source row (~28K of 600K)
__global__ __launch_bounds__(256) void csr_fill(const int* __restrict__ erow,
                                                const int* __restrict__ ecol,
                                                const float* __restrict__ ev, int E,
                                                const int* __restrict__ markU,
                                                int* __restrict__ fillptr,
                                                int* __restrict__ ccol,
                                                float* __restrict__ cval) {
    int e = blockIdx.x * 256 + threadIdx.x;
    if (e >= E) return;
    int r = erow[e];
    if (!markU[r]) return;
    int p = atomicAdd(&fillptr[r], 1);  // distributed (~10 per address)
    ccol[p] = ecol[e];
    cval[p] = ev[e];
}

// ---------------- compute kernels ----------------

// Y[rows[i]] = X[rows[i]] @ W. 32 rows/block-iteration; each thread: 4 rows x 4 cols.
__global__ __launch_bounds__(256) void gemm_rows(const float* __restrict__ X,
                                                 const float* __restrict__ W,
                                                 float* __restrict__ Y,
                                                 const int* __restrict__ rows,
                                                 const int* __restrict__ cntp) {
    __shared__ float xs[32 * GD];  // 16 KB
    __shared__ int rid[32];
    int t = threadIdx.x;
    int cnt = *cntp;
    int ngroups = (cnt + 31) >> 5;
    for (int g = blockIdx.x; g < ngroups; g += gridDim.x) {
        __syncthreads();  // protect xs/rid reuse across grid-stride iterations
        if (t < 32) {
            int gi = g * 32 + t;
            rid[t] = (gi < cnt) ? rows[gi] : -1;
        }
        __syncthreads();
        for (int u = t; u < 32 * 32; u += 256) {
            int r = rid[u >> 5];
            if (r >= 0) ((float4*)xs)[u] = ((const float4*)(X + (size_t)r * GD))[u & 31];
        }
        __syncthreads();

        int c4 = (t & 31) * 4;
        int rg = (t >> 5) * 4;
        float4 a0 = {0, 0, 0, 0}, a1 = {0, 0, 0, 0}, a2 = {0, 0, 0, 0}, a3 = {0, 0, 0, 0};
        const float* x0 = xs + (size_t)(rg + 0) * GD;
        const float* x1 = xs + (size_t)(rg + 1) * GD;
        const float* x2 = xs + (size_t)(rg + 2) * GD;
        const float* x3 = xs + (size_t)(rg + 3) * GD;
#pragma unroll 4
        for (int k = 0; k < GD; k += 4) {
            float4 xv0 = *(const float4*)(x0 + k);
            float4 xv1 = *(const float4*)(x1 + k);
            float4 xv2 = *(const float4*)(x2 + k);
            float4 xv3 = *(const float4*)(x3 + k);
            float4 w0 = *(const float4*)(W + (size_t)(k + 0) * GD + c4);
            float4 w1 = *(const float4*)(W + (size_t)(k + 1) * GD + c4);
            float4 w2 = *(const float4*)(W + (size_t)(k + 2) * GD + c4);
            float4 w3 = *(const float4*)(W + (size_t)(k + 3) * GD + c4);
            a0.x += xv0.x * w0.x + xv0.y * w1.x + xv0.z * w2.x + xv0.w * w3.x;
            a0.y += xv0.x * w0.y + xv0.y * w1.y + xv0.z * w2.y + xv0.w * w3.y;
            a0.z += xv0.x * w0.z + xv0.y * w1.z + xv0.z * w2.z + xv0.w * w3.z;
            a0.w += xv0.x * w0.w + xv0.y * w1.w + xv0.z * w2.w + xv0.w * w3.w;
            a1.x += xv1.x * w0.x + xv1.y * w1.x + xv1.z * w2.x + xv1.w * w3.x;
            a1.y += xv1.x * w0.y + xv1.y * w1.y + xv1.z * w2.y + xv1.w * w3.y;
            a1.z += xv1.x * w0.z + xv1.y * w1.z + xv1.z * w2.z + xv1.w * w3.z;
            a1.w += xv1.x * w0.w + xv1.y * w1.w + xv1.z * w2.w + xv1.w * w3.w;
            a2.x += xv2.x * w0.x + xv2.y * w1.x + xv2.z * w2.x + xv2.w * w3.x;
            a2.y += xv2.x * w0.y + xv2.y * w1.y + xv2.z * w2.y + xv2.w * w3.y;
            a2.z += xv2.x * w0.z + xv2.y * w1.z + xv2.z * w2.z + xv2.w * w3.z;
            a2.w += xv2.x * w0.w + xv2.y * w1.w + xv2.z * w2.w + xv2.w * w3.w;
            a3.x += xv3.x * w0.x + xv3.y * w1.x + xv3.z * w2.x + xv3.w * w3.x;
            a3.y += xv3.x * w0.y + xv3.y * w1.y + xv3.z * w2.y + xv3.w * w3.y;
            a3.z += xv3.x * w0.z + xv3.y * w1.z + xv3.z * w2.z + xv3.w * w3.z;
            a3.w += xv3.x * w0.w + xv3.y * w1.w + xv3.z * w2.w + xv3.w * w3.w;
        }
        int r;
        r = rid[rg + 0]; if (r >= 0) *(float4*)(Y + (size_t)r * GD + c4) = a0;
        r = rid[rg + 1]; if (r >= 0) *(float4*)(Y + (size_t)r * GD + c4) = a1;
        r = rid[rg + 2]; if (r >= 0) *(float4*)(Y + (size_t)r * GD + c4) = a2;
        r = rid[rg + 3]; if (r >= 0) *(float4*)(Y + (size_t)r * GD + c4) = a3;
    }
}

// gather aggregation + alpha-blend + relu over listed rows (no atomics)
__global__ __launch_bounds__(128) void agg_blend(const float* __restrict__ S,
                                                 const float* __restrict__ init,
                                                 const int* __restrict__ rowstart,
                                                 const int* __restrict__ cnt,
                                                 const int* __restrict__ ccol,
                                                 const float* __restrict__ cval,
                                                 const int* __restrict__ rows,
                                                 const int* __restrict__ cntp,
                                                 float* __restrict__ out) {
    int t = threadIdx.x;
    int n = *cntp;
    for (int i = blockIdx.x; i < n; i += gridDim.x) {
        int r = rows[i];
        int s = rowstart[r], c = cnt[r];
        float acc = 0.f;
        for (int k = 0; k < c; ++k) {
            int col = ccol[s + k];               // uniform -> broadcast
            float v = cval[s + k];
            acc += S[(size_t)col * GD + t] * v;  // coalesced 512B row read
        }
        out[(size_t)r * GD + t] = fmaxf(0.1f * acc + 0.9f * init[(size_t)r * GD + t], 0.0f);
    }
}

// layer-2 aggregation fused into RNNCell + L2 normalize. One block (128 thr) per b.
__global__ __launch_bounds__(128) void final_rnn(const float* __restrict__ S2,
                                                 const float* __restrict__ init,
                                                 const float* __restrict__ patient,
                                                 const float* __restrict__ timediffs,
                                                 const float* __restrict__ features,
                                                 const float* __restrict__ W_ih,
                                                 const float* __restrict__ b_ih,
                                                 const float* __restrict__ W_hh,
                                                 const float* __restrict__ b_hh,
                                                 const int* __restrict__ codeid,
                                                 const int* __restrict__ patientid,
                                                 const int* __restrict__ rowstart,
                                                 const int* __restrict__ cnt,
                                                 const int* __restrict__ ccol,
                                                 const float* __restrict__ cval,
                                                 float* __restrict__ out) {
    __shared__ float in1[257];
    __shared__ float ce[GD];
    __shared__ float red[GD];
    int b = blockIdx.x;
    int j = threadIdx.x;
    int cid = codeid[b];
    int pid = patientid[0];

    int s = rowstart[cid], c = cnt[cid];
    float agg = 0.f;
    for (int k = 0; k < c; ++k)
        agg += cval[s + k] * S2[(size_t)ccol[s + k] * GD + j];

    ce[j] = fmaxf(0.1f * agg + 0.9f * init[(size_t)cid * GD + j], 0.0f);
    in1[j] = patient[(size_t)pid * GD + j];
    in1[GD + 1 + j] = features[(size_t)b * GD + j];
    if (j == 0) in1[GD] = timediffs[b];
    __syncthreads();

    float acc = b_ih[j] + b_hh[j];
    const float* wih = W_ih + (size_t)j * 257;
#pragma unroll 8
    for (int k = 0; k < 257; ++k) acc += in1[k] * wih[k];
    const float* whh = W_hh + (size_t)j * GD;
#pragma unroll 8
    for (int k = 0; k < GD; ++k) acc += ce[k] * whh[k];
    float h = tanhf(acc);

    red[j] = h * h;
    __syncthreads();
    for (int st = 64; st > 0; st >>= 1) {
        if (j < st) red[j] += red[j + st];
        __syncthreads();
    }
    float nrm = fmaxf(sqrtf(red[0]), 1e-12f);
    out[(size_t)b * GD + j] = h / nrm;
}

extern "C" void kernel_launch(void* const* d_in, const int* in_sizes, int n_in,
                              void* d_out, int out_size, void* d_ws, size_t ws_size,
                              hipStream_t stream) {
    const float* code_dynamic = (const float*)d_in[0];
    const float* init_cd      = (const float*)d_in[1];
    const float* patient      = (const float*)d_in[2];
    const float* timediffs    = (const float*)d_in[3];
    const float* features     = (const float*)d_in[4];
    const float* edge_val     = (const float*)d_in[5];
    const float* W1           = (const float*)d_in[6];
    const float* W2           = (const float*)d_in[7];
    const float* W_ih         = (const float*)d_in[8];
    const float* b_ih         = (const float*)d_in[9];
    const float* W_hh         = (const float*)d_in[10];
    const float* b_hh         = (const float*)d_in[11];
    const int* edge_row       = (const int*)d_in[12];
    const int* edge_col       = (const int*)d_in[13];
    const int* codeid         = (const int*)d_in[14];
    const int* patientid      = (const int*)d_in[15];

    int N = in_sizes[0] / GD;   // 60000
    int E = in_sizes[5];        // 600000
    int B = in_sizes[14];       // 256
    size_t nd = (size_t)N * GD;

    // workspace layout (all segments 16B-aligned: nd, E, N are multiples of 4)
    float* bufA    = (float*)d_ws;           // support1 / support2 (N*128 f32)
    float* bufB    = bufA + nd;              // x1 (N*128 f32)
    int*   ccol    = (int*)(bufB + nd);      // E  restricted CSR cols
    float* cval    = (float*)(ccol + E);     // E  restricted CSR vals
    int*   cntarr  = (int*)(cval + E);       // N  -- zeroed region start
    int*   mark2   = cntarr + N;             // N  codeid rows
    int*   markU   = mark2 + N;              // N  rows1 u codeid
    int*   mark0   = markU + N;              // N  rows needing layer-1 gemm
    int*   cnts    = mark0 + N;              // 8 ints: [cntU, cnt0, gAlloc] -- zeroed end
    int*   rowstart= cnts + 8;               // N
    int*   fillptr = rowstart + N;           // N
    int*   rowsU   = fillptr + N;            // N
    int*   rows0   = rowsU + N;              // N

    int eb  = (E + 255) / 256;
    int nbs = (N + 255) / 256;

    // zero marks/counters with our own kernel (runtime fillBuffer ran at 25 GB/s / 39 us)
    int n4 = (4 * N + 8) / 4;  // exact: N multiple of 4
    zero_ints<<<(n4 + 255) / 256, 256, 0, stream>>>((int4*)cntarr, n4);

    // dependency cone via mark propagation (no contended atomics, no full CSR)
    mark_codeids<<<(B + 255) / 256, 256, 0, stream>>>(codeid, B, mark2, markU);
    mark_next<<<eb, 256, 0, stream>>>(edge_row, edge_col, E, mark2, markU);
    expand_and_count<<<eb, 256, 0, stream>>>(edge_row, edge_col, E, markU, mark0, cntarr);

    // fused CSR-offset allocation + dual compaction (single N-pass)
    scan_compact<<<nbs, 256, 0, stream>>>(cntarr, markU, mark0, N,
                                          rowstart, fillptr, &cnts[2],
                                          rowsU, &cnts[0], rows0, &cnts[1]);
    csr_fill<<<eb, 256, 0, stream>>>(edge_row, edge_col, edge_val, E, markU, fillptr, ccol, cval);

    // layer 1: support1 on rows0 (~28K rows), gather-agg + blend + relu on rowsU (~2.8K)
    gemm_rows<<<1024, 256, 0, stream>>>(code_dynamic, W1, bufA, rows0, &cnts[1]);
    agg_blend<<<2048, 128, 0, stream>>>(bufA, init_cd, rowstart, cntarr, ccol, cval,
                                        rowsU, &cnts[0], bufB);

    // layer 2: support2 on rowsU (codeid-row aggregation fused into final_rnn)
    gemm_rows<<<1024, 256, 0, stream>>>(bufB, W2, bufA, rowsU, &cnts[0]);

    // RNNCell + L2 normalize (fused layer-2 gather-aggregation)
    final_rnn<<<B, 128, 0, stream>>>(bufA, init_cd, patient, timediffs, features,
                                     W_ih, b_ih, W_hh, b_hh, codeid, patientid,
                                     rowstart, cntarr, ccol, cval,
                                     (float*)d_out);
}